// Round 15
// baseline (50.825 us; speedup 1.0000x reference)
//
#include <hip/hip_runtime.h>
#include <hip/hip_bf16.h>

// Problem: B=4096, D_IN=D_H=K=1024.
//   x = input_ @ fq(Wi,4).T + bi ; h = hidden @ fq(Wr,4).T + br
//   out = tanh(LN(x) + LN(h))
// ws layout:
//   +0      : bmax f32[512]
//   +2048   : scales f32[2]
//   +4096   : Qi bf16 ints, 2 MB
//   +2M+4096: Qr bf16 ints, 2 MB
//   +4M+4096: Abf bf16, 8 MB
//   +12M+..: Hbf bf16, 8 MB
//   +20M+..: Xq bf16, 8 MB
//   +28M+..: Hq bf16, 8 MB

typedef float  f32x4  __attribute__((ext_vector_type(4)));
typedef __bf16 bf16x8 __attribute__((ext_vector_type(8)));
typedef __bf16 bf16x4 __attribute__((ext_vector_type(4)));

#define KDIM 1024

// ---------------- fused: weight absmax (blocks 0..511) + activation cvt (512..2559) ----------------
__global__ __launch_bounds__(256)
void prep1_k(const float* __restrict__ A, const float* __restrict__ Hh,
             const float* __restrict__ Wi, const float* __restrict__ Wr,
             float* __restrict__ bmax,
             __bf16* __restrict__ Abf, __bf16* __restrict__ Hbf)
{
    const int b = blockIdx.x, t = threadIdx.x;
    if (b < 512) {
        const int tensor = b >> 8;
        const float* W = tensor ? Wr : Wi;
        const int lane = t & 63, wid = t >> 6;
        const f32x4* p = (const f32x4*)W;
        const size_t base = (size_t)(b & 255) * 1024;
        float m = 0.f;
#pragma unroll
        for (int k = 0; k < 4; ++k) {
            f32x4 v = p[base + k * 256 + t];
            m = fmaxf(m, fmaxf(fmaxf(fabsf(v[0]), fabsf(v[1])),
                               fmaxf(fabsf(v[2]), fabsf(v[3]))));
        }
#pragma unroll
        for (int o = 32; o >= 1; o >>= 1) m = fmaxf(m, __shfl_xor(m, o));
        __shared__ float wm_[4];
        if (lane == 0) wm_[wid] = m;
        __syncthreads();
        if (t == 0) bmax[b] = fmaxf(fmaxf(wm_[0], wm_[1]), fmaxf(wm_[2], wm_[3]));
        return;
    }
    const int c = b - 512;
    const float* src = (c < 1024) ? A : Hh;
    __bf16* dst = (c < 1024) ? Abf : Hbf;
    const int base = (c & 1023) * 4096;
#pragma unroll
    for (int j = 0; j < 2; ++j) {
        const int e = base + (j * 256 + t) * 8;
        f32x4 v0 = ((const f32x4*)(src + e))[0];
        f32x4 v1 = ((const f32x4*)(src + e))[1];
        bf16x8 o;
#pragma unroll
        for (int i = 0; i < 4; ++i) {
            o[i]     = (__bf16)v0[i];
            o[i + 4] = (__bf16)v1[i];
        }
        *(bf16x8*)(dst + e) = o;
    }
}

// ---------------- quantize weights to integer bf16 ----------------
__global__ __launch_bounds__(256)
void quant_k(const float* __restrict__ Wi, const float* __restrict__ Wr,
             const float* __restrict__ bmax, float* __restrict__ scales,
             __bf16* __restrict__ Qi, __bf16* __restrict__ Qr)
{
    const int tensor = blockIdx.x >> 8;
    const int b = blockIdx.x & 255;
    const int t = threadIdx.x;
    const int lane = t & 63, wid = t >> 6;

    float m = bmax[tensor * 256 + t];
#pragma unroll
    for (int o = 32; o >= 1; o >>= 1) m = fmaxf(m, __shfl_xor(m, o));
    __shared__ float wm_[4];
    if (lane == 0) wm_[wid] = m;
    __syncthreads();
    m = fmaxf(fmaxf(wm_[0], wm_[1]), fmaxf(wm_[2], wm_[3]));
    const float s = m / 7.0f;
    if (t == 0 && b == 0) scales[tensor] = s;

    const float* W = tensor ? Wr : Wi;
    __bf16* Q = tensor ? Qr : Qi;
#pragma unroll
    for (int j = 0; j < 2; ++j) {
        const int e = b * 4096 + (j * 256 + t) * 8;
        f32x4 v0 = ((const f32x4*)(W + e))[0];
        f32x4 v1 = ((const f32x4*)(W + e))[1];
        bf16x8 o;
#pragma unroll
        for (int i = 0; i < 4; ++i) {
            o[i]     = (__bf16)rintf(v0[i] / s);
            o[i + 4] = (__bf16)rintf(v1[i] / s);
        }
        *(bf16x8*)(Q + e) = o;
    }
}

// ---------------- dual bf16 MFMA GEMM: 128x64 tile, 4 waves, 4 BLOCKS/CU ----------------
// Occupancy push (m97/m114 mechanism): grid 1024 = exactly 4.0 blocks/CU,
// single-buffered 24 KB LDS (A 16 KB + B 8 KB); waves cap residency at 4
// blocks (16 waves/CU). The per-iter vmcnt(0)+barrier drain is covered by
// the 3 SIBLING blocks' MFMAs — the overlap every 1-2-block/CU config lacked.
// Inner loop keeps round-14's proven grouped reads + counted lgkm + setprio.
// Per-output FP op sequence (fragment bytes, kt/kk order) unchanged
// => bit-identical output to rounds 5-14.
__global__ __launch_bounds__(256, 4)
void gemm_dual(const __bf16* __restrict__ A0, const __bf16* __restrict__ A1,
               const __bf16* __restrict__ W0, const __bf16* __restrict__ W1,
               __bf16* __restrict__ C0, __bf16* __restrict__ C1)
{
    __shared__ bf16x8 lds[1536];   // A: 0..1023 (128 rows), B: 1024..1535 (64 rows)

    // XCD-aware bijective swizzle (1024 blocks, 8 XCDs)
    const int b = blockIdx.x;
    const int swz = (b & 7) * 128 + (b >> 3);
    const int which = swz >> 9;
    const int r = swz & 511;
    const int bm = r >> 4, bn = r & 15;   // bm 0..31 (M/128), bn 0..15 (N/64)

    const __bf16* A = which ? A1 : A0;
    const __bf16* W = which ? W1 : W0;
    __bf16*       C = which ? C1 : C0;

    const int t = threadIdx.x;
    const int l = t & 63, w = t >> 6;
    const int wm = w >> 1, wn = w & 1;    // wave grid 2M x 2N, per-wave 64x32
    const int l15 = l & 15, l7 = l & 7, lq = l >> 4;

    const __bf16* gA = A + (size_t)(bm * 128) * KDIM;
    const __bf16* gB = W + (size_t)(bn * 64) * KDIM;

    // staging source offsets (element units), pre-swizzled for linear LDS
    int srcA[4], srcB[2];
#pragma unroll
    for (int j = 0; j < 4; ++j) {
        const int c = j * 256 + t;        // A chunk 0..1023 (row 0..127)
        const int row = c >> 3, g = (c & 7) ^ (row & 7);
        srcA[j] = row * KDIM + g * 8;
    }
#pragma unroll
    for (int j = 0; j < 2; ++j) {
        const int c = j * 256 + t;        // B chunk 0..511 (row 0..63)
        const int row = c >> 3, g = (c & 7) ^ (row & 7);
        srcB[j] = row * KDIM + g * 8;
    }

#define STAGE(kt)                                                              \
    do {                                                                       \
        _Pragma("unroll")                                                      \
        for (int j = 0; j < 4; ++j)                                            \
            __builtin_amdgcn_global_load_lds(                                  \
                (const __attribute__((address_space(1))) unsigned*)(gA + srcA[j] + (kt) * 64), \
                (__attribute__((address_space(3))) unsigned*)(&lds[(j) * 256 + t]), \
                16, 0, 0);                                                     \
        _Pragma("unroll")                                                      \
        for (int j = 0; j < 2; ++j)                                            \
            __builtin_amdgcn_global_load_lds(                                  \
                (const __attribute__((address_space(1))) unsigned*)(gB + srcB[j] + (kt) * 64), \
                (__attribute__((address_space(3))) unsigned*)(&lds[1024 + (j) * 256 + t]), \
                16, 0, 0);                                                     \
    } while (0)

    // fragment LDS chunk offsets [kk][idx]
    int offA[2][4], offB[2][2];
#pragma unroll
    for (int kk = 0; kk < 2; ++kk) {
        const int kq = kk * 4 + lq;
#pragma unroll
        for (int mi = 0; mi < 4; ++mi)
            offA[kk][mi] = (wm * 64 + mi * 16 + l15) * 8 + (kq ^ l7);
#pragma unroll
        for (int ni = 0; ni < 2; ++ni)
            offB[kk][ni] = 1024 + (wn * 32 + ni * 16 + l15) * 8 + (kq ^ l7);
    }

    f32x4 acc[4][2];
#pragma unroll
    for (int mi = 0; mi < 4; ++mi)
#pragma unroll
        for (int ni = 0; ni < 2; ++ni) acc[mi][ni] = (f32x4){0.f, 0.f, 0.f, 0.f};

#define LGKM(n)                                                                \
    do { asm volatile("s_waitcnt lgkmcnt(" #n ")" ::: "memory");               \
         __builtin_amdgcn_sched_barrier(0); } while (0)

#pragma unroll
    for (int kt = 0; kt < 16; ++kt) {
        // buf free: all waves' reads retired (lgkm(0)) before last barrier
        STAGE(kt);                                          // 6 gll
        asm volatile("s_waitcnt vmcnt(0)" ::: "memory");    // buf staged
        __builtin_amdgcn_sched_barrier(0);
        __builtin_amdgcn_s_barrier();                       // drain covered by 3 siblings

        // ordered read groups: grp0 = kk0 (6 reads), grp1 = kk1 (6 reads)
        bf16x8 af[2][4], bfv[2][2];
#pragma unroll
        for (int ni = 0; ni < 2; ++ni) bfv[0][ni] = lds[offB[0][ni]];
#pragma unroll
        for (int mi = 0; mi < 4; ++mi) af[0][mi]  = lds[offA[0][mi]];
        __builtin_amdgcn_sched_barrier(0);
#pragma unroll
        for (int ni = 0; ni < 2; ++ni) bfv[1][ni] = lds[offB[1][ni]];
#pragma unroll
        for (int mi = 0; mi < 4; ++mi) af[1][mi]  = lds[offA[1][mi]];
        __builtin_amdgcn_sched_barrier(0);

        LGKM(6);                  // grp0 landed
        __builtin_amdgcn_s_setprio(1);
#pragma unroll
        for (int mi = 0; mi < 4; ++mi)
#pragma unroll
            for (int ni = 0; ni < 2; ++ni)
                acc[mi][ni] = __builtin_amdgcn_mfma_f32_16x16x32_bf16(
                    bfv[0][ni], af[0][mi], acc[mi][ni], 0, 0, 0);
        __builtin_amdgcn_s_setprio(0);

        LGKM(0);                  // grp1 landed; all reads of buf retired
        __builtin_amdgcn_s_setprio(1);
#pragma unroll
        for (int mi = 0; mi < 4; ++mi)
#pragma unroll
            for (int ni = 0; ni < 2; ++ni)
                acc[mi][ni] = __builtin_amdgcn_mfma_f32_16x16x32_bf16(
                    bfv[1][ni], af[1][mi], acc[mi][ni], 0, 0, 0);
        __builtin_amdgcn_s_setprio(0);

        if (kt < 15) __builtin_amdgcn_s_barrier();   // reads retired before next STAGE
    }

    // C write (swapped-operand layout): batch = lane&15 (+mi*16),
    // feat = (lane>>4)*4 + rr (+ni*16); one 8B bf16x4 store per fragment
    const int batch0 = bm * 128 + wm * 64 + l15;
    const int feat0  = bn * 64 + wn * 32 + (lq << 2);
#pragma unroll
    for (int mi = 0; mi < 4; ++mi)
#pragma unroll
        for (int ni = 0; ni < 2; ++ni) {
            bf16x4 o;
#pragma unroll
            for (int rr = 0; rr < 4; ++rr) o[rr] = (__bf16)acc[mi][ni][rr];
            *(bf16x4*)(C + (size_t)(batch0 + mi * 16) * KDIM + feat0 + ni * 16) = o;
        }
#undef STAGE
#undef LGKM
}

// ---------------- fused scale+bias, LN(x), LN(h), tanh — one row per WAVE ----------------
__global__ __launch_bounds__(256)
void ln_tanh_k(const __bf16* __restrict__ X, const __bf16* __restrict__ Hh,
               const float* __restrict__ bi, const float* __restrict__ br,
               const float* __restrict__ scales, float* __restrict__ out)
{
    const int t = threadIdx.x;
    const int lane = t & 63, wid = t >> 6;
    const int row = blockIdx.x * 4 + wid;
    const float si = scales[0];
    const float sr = scales[1];

    const bf16x8* xp = (const bf16x8*)(X  + (size_t)row * 1024 + lane * 16);
    const bf16x8* hp = (const bf16x8*)(Hh + (size_t)row * 1024 + lane * 16);
    bf16x8 xv0 = xp[0], xv1 = xp[1];
    bf16x8 hv0 = hp[0], hv1 = hp[1];

    float xs[16], hs[16];
    float sx = 0.f, sh = 0.f;
#pragma unroll
    for (int q = 0; q < 4; ++q) {
        f32x4 bviq = ((const f32x4*)bi)[lane * 4 + q];
        f32x4 bvrq = ((const f32x4*)br)[lane * 4 + q];
#pragma unroll
        for (int j = 0; j < 4; ++j) {
            const int e = q * 4 + j;
            const float xf = (e < 8) ? (float)xv0[e] : (float)xv1[e - 8];
            const float hf = (e < 8) ? (float)hv0[e] : (float)hv1[e - 8];
            xs[e] = xf * si + bviq[j];
            hs[e] = hf * sr + bvrq[j];
            sx += xs[e]; sh += hs[e];
        }
    }

#pragma unroll
    for (int o = 32; o >= 1; o >>= 1) { sx += __shfl_xor(sx, o); sh += __shfl_xor(sh, o); }
    const float mx = sx * (1.0f / 1024.0f), mh = sh * (1.0f / 1024.0f);

    float vx = 0.f, vh = 0.f;
#pragma unroll
    for (int e = 0; e < 16; ++e) {
        xs[e] -= mx; hs[e] -= mh;
        vx += xs[e] * xs[e]; vh += hs[e] * hs[e];
    }
#pragma unroll
    for (int o = 32; o >= 1; o >>= 1) { vx += __shfl_xor(vx, o); vh += __shfl_xor(vh, o); }
    const float rsx = rsqrtf(vx * (1.0f / 1024.0f) + 1e-5f);
    const float rsh = rsqrtf(vh * (1.0f / 1024.0f) + 1e-5f);

    float* op = out + (size_t)row * 1024 + lane * 16;
#pragma unroll
    for (int q = 0; q < 4; ++q) {
        f32x4 o4;
#pragma unroll
        for (int j = 0; j < 4; ++j) {
            const int e = q * 4 + j;
            o4[j] = tanhf(xs[e] * rsx + hs[e] * rsh);
        }
        ((f32x4*)op)[q] = o4;
    }
}

extern "C" void kernel_launch(void* const* d_in, const int* in_sizes, int n_in,
                              void* d_out, int out_size, void* d_ws, size_t ws_size,
                              hipStream_t stream)
{
    const float* input_ = (const float*)d_in[0];
    const float* hidden = (const float*)d_in[1];
    const float* Wi     = (const float*)d_in[2];
    const float* bi     = (const float*)d_in[3];
    const float* Wr     = (const float*)d_in[4];
    const float* br     = (const float*)d_in[5];
    float* out = (float*)d_out;

    char* ws = (char*)d_ws;
    float* bmax   = (float*)ws;
    float* scales = (float*)(ws + 2048);
    __bf16* Qi  = (__bf16*)(ws + 4096);
    __bf16* Qr  = (__bf16*)(ws + 4096 + (1u << 21));
    __bf16* Abf = (__bf16*)(ws + 4096 + (2u << 21));
    __bf16* Hbf = (__bf16*)(ws + 4096 + (2u << 21) + (1u << 23));
    __bf16* Xq  = (__bf16*)(ws + 4096 + (2u << 21) + (2u << 23));
    __bf16* Hq  = (__bf16*)(ws + 4096 + (2u << 21) + (3u << 23));

    prep1_k<<<2560, 256, 0, stream>>>(input_, hidden, Wi, Wr, bmax, Abf, Hbf);
    quant_k<<<512, 256, 0, stream>>>(Wi, Wr, bmax, scales, Qi, Qr);
    gemm_dual<<<1024, 256, 0, stream>>>(Abf, Hbf, Qi, Qr, Xq, Hq);
    ln_tanh_k<<<1024, 256, 0, stream>>>(Xq, Hq, bi, br, scales, out);
}